// Round 15
// baseline (75.293 us; speedup 1.0000x reference)
//
#include <hip/hip_runtime.h>

#define BT 256           // 4 waves per block
#define ROWB 128         // LDS row stride: 32 words = 8 x 16B slots
#define WLDS (64 * ROWB) // 8192 B per wave -> 32768 B per block (5 blocks = 160 KiB/CU)
// A-row (logical): 64 shorts = 48 bf16 obs + 16 zeros (K-pad + gather sentinel)
// strip (per column-tile): logical words 0..15, reused 3x (overlays A k=0..31 only)
// A k=32..63 (logical bytes 64..127) SURVIVES the strip -> afrag1 re-read per tile
// V-area (post-VI): logical words 0..15 + zero sentinel word 16
// All LDS accesses XOR-swizzled per row: phys_byte = logical_byte ^ ((row&7)<<4)

// Compiler-only fence: orders LDS ops across overlay phases (HW DS is in-order per wave).
#define MEMFENCE asm volatile("" ::: "memory")

typedef __attribute__((ext_vector_type(8))) short short8;
typedef __attribute__((ext_vector_type(4))) float f32x4;
typedef __attribute__((ext_vector_type(4))) unsigned int u32x4;
typedef _Float16 h2 __attribute__((ext_vector_type(2)));

__device__ inline unsigned cvtpkbf(float a, float b) {   // 2xf32 -> 2xbf16 (RNE)
    unsigned d;
    asm("v_cvt_pk_bf16_f32 %0, %1, %2" : "=v"(d) : "v"(a), "v"(b));
    return d;
}
__device__ inline float b2f(short s) {
    unsigned u = ((unsigned)(unsigned short)s) << 16;
    return __builtin_bit_cast(float, u);
}
__device__ inline unsigned pkrtz(float a, float b) {     // 2xf32 -> 2xf16 (RTZ)
    unsigned d;
    asm("v_cvt_pkrtz_f16_f32 %0, %1, %2" : "=v"(d) : "v"(a), "v"(b));
    return d;
}
__device__ inline unsigned pkfma(unsigned a, unsigned b, unsigned c) {
    unsigned d;
    asm("v_pk_fma_f16 %0, %1, %2, %3" : "=v"(d) : "v"(a), "v"(b), "v"(c));
    return d;
}
// fma with src1 halves SWAPPED: res.lo = a.lo*b.hi + c.lo ; res.hi = a.hi*b.lo + c.hi
__device__ inline unsigned pkfma_swap1(unsigned a, unsigned b, unsigned c) {
    unsigned d;
    asm("v_pk_fma_f16 %0, %1, %2, %3 op_sel:[0,1,0] op_sel_hi:[1,0,1]"
        : "=v"(d) : "v"(a), "v"(b), "v"(c));
    return d;
}
__device__ inline unsigned pkmax(unsigned a, unsigned b) {
    unsigned d;
    asm("v_pk_max_f16 %0, %1, %2" : "=v"(d) : "v"(a), "v"(b));
    return d;
}
__device__ inline unsigned pksub(unsigned a, unsigned b) {   // a - b
    unsigned d;
    asm("v_pk_add_f16 %0, %1, %2 neg_lo:[0,1] neg_hi:[0,1]" : "=v"(d) : "v"(a), "v"(b));
    return d;
}
__device__ inline unsigned pkneg(unsigned b) {               // -b
    unsigned d;
    asm("v_pk_add_f16 %0, 0, %1 neg_lo:[0,1] neg_hi:[0,1]" : "=v"(d) : "v"(b));
    return d;
}

// one VI step; pack (h,j): lo=V[h][j], hi=V[h][j+2]
// Boundary halves via half-masked p (pLm.lo=0, pRm.hi=0) + op_sel swap (exact).
__device__ inline void vistep(const unsigned (&S)[4][2], unsigned (&D)[4][2],
                              const unsigned (&pp)[4][2],
                              const unsigned (&pLm)[4], const unsigned (&pRm)[4],
                              const unsigned (&aL)[4][2], const unsigned (&aR)[4][2],
                              const unsigned (&aU)[4][2], const unsigned (&aD)[4][2])
{
    #pragma unroll
    for (int h = 0; h < 4; ++h) {
        {
            unsigned cL = pkfma_swap1(pLm[h], S[h][1], aL[h][0]);
            unsigned cR = pkfma(pp[h][0], S[h][1], aR[h][0]);
            unsigned tU = (h > 0) ? pkfma(pp[h][0], S[h-1][0], aU[h][0]) : aU[h][0];
            unsigned tD = (h < 3) ? pkfma(pp[h][0], S[h+1][0], aD[h][0]) : aD[h][0];
            unsigned m1 = pkmax(S[h][0], cL);
            unsigned m2 = pkmax(cR, tU);
            D[h][0] = pkmax(pkmax(m1, m2), tD);
        }
        {
            unsigned cL = pkfma(pp[h][1], S[h][0], aL[h][1]);
            unsigned cR = pkfma_swap1(pRm[h], S[h][0], aR[h][1]);
            unsigned tU = (h > 0) ? pkfma(pp[h][1], S[h-1][1], aU[h][1]) : aU[h][1];
            unsigned tD = (h < 3) ? pkfma(pp[h][1], S[h+1][1], aD[h][1]) : aD[h][1];
            unsigned m1 = pkmax(S[h][1], cL);
            unsigned m2 = pkmax(cR, tU);
            D[h][1] = pkmax(pkmax(m1, m2), tD);
        }
    }
}

// one column-tile, register-lean: frag0 pass (bf0 live) -> frag1 pass (bf1 live,
// afrag1 re-read from LDS bytes 64..127 which the strip never touches) ->
// swizzled scatter -> readback 16 f32.
__device__ inline void tile_pass(int n, char* wbase, int jn, int g, int xb, int xr,
                                 const short8 (&afrag0)[4],
                                 const float* __restrict__ PhiW, float bn,
                                 float (&rv)[16])
{
    const float* wrow = PhiW + (16*n + jn) * 48;
    f32x4 acc[4];
    {
        short8 bf0;
        float4 q0 = *reinterpret_cast<const float4*>(wrow + 8*g);
        float4 q1 = *reinterpret_cast<const float4*>(wrow + 8*g + 4);
        u32x4 t0;
        t0[0] = cvtpkbf(q0.x, q0.y); t0[1] = cvtpkbf(q0.z, q0.w);
        t0[2] = cvtpkbf(q1.x, q1.y); t0[3] = cvtpkbf(q1.z, q1.w);
        bf0 = __builtin_bit_cast(short8, t0);
        #pragma unroll
        for (int m = 0; m < 4; ++m) {
            acc[m] = (f32x4){bn, bn, bn, bn};
            acc[m] = __builtin_amdgcn_mfma_f32_16x16x32_bf16(afrag0[m], bf0, acc[m], 0, 0, 0);
        }
    }
    {
        short8 bf1;
        u32x4 tz = {0u, 0u, 0u, 0u};
        if (g < 2) {   // k = 32+8g..+7 valid only for g<2; k>=48 zero pad
            float4 q2 = *reinterpret_cast<const float4*>(wrow + 32 + 8*g);
            float4 q3 = *reinterpret_cast<const float4*>(wrow + 36 + 8*g);
            tz[0] = cvtpkbf(q2.x, q2.y); tz[1] = cvtpkbf(q2.z, q2.w);
            tz[2] = cvtpkbf(q3.x, q3.y); tz[3] = cvtpkbf(q3.z, q3.w);
        }
        bf1 = __builtin_bit_cast(short8, tz);
        #pragma unroll
        for (int m = 0; m < 4; ++m) {
            const char* rp = wbase + (m*16 + jn) * ROWB;
            short8 a1 = *reinterpret_cast<const short8*>(rp + ((64 + 16*g) ^ xr));
            acc[m] = __builtin_amdgcn_mfma_f32_16x16x32_bf16(a1, bf1, acc[m], 0, 0, 0);
        }
    }
    // scatter D: lane holds col 16n+jn of rows R=m*16+4g+r; word jn, swizzled
    #pragma unroll
    for (int m = 0; m < 4; ++m)
        #pragma unroll
        for (int r = 0; r < 4; ++r) {
            int R = m*16 + 4*g + r;
            int byte = R * ROWB + ((jn * 4) ^ (((4*g + r) & 7) << 4));
            *reinterpret_cast<float*>(wbase + byte) = acc[m][r];
        }
    MEMFENCE;   // scatter before readback (RAW; in-order DS)
    char* myrow = wbase + ((threadIdx.x & 63) * ROWB);
    #pragma unroll
    for (int s = 0; s < 4; ++s) {
        f32x4 t = *reinterpret_cast<const f32x4*>(myrow + ((s * 16) ^ xb));
        rv[4*s+0] = t[0]; rv[4*s+1] = t[1]; rv[4*s+2] = t[2]; rv[4*s+3] = t[3];
    }
    MEMFENCE;   // readback before next tile's scatter (WAR)
}

__global__ __launch_bounds__(BT, 5) void vin_kernel(
    const float* __restrict__ obs,
    const float* __restrict__ PhiW,
    const float* __restrict__ Phib,
    const float* __restrict__ LW,
    const float* __restrict__ Lb,
    float* __restrict__ out, int Btot)
{
    __shared__ __align__(16) char smem[4 * WLDS];   // 32768 B
    const int tid  = threadIdx.x;
    const int lane = tid & 63;
    const int wid  = tid >> 6;
    const int b    = blockIdx.x * BT + tid;
    // Btot % 64 == 0, waves entirely in or out; no barriers -> early return safe
    if (b >= Btot) return;

    char* wbase = smem + wid * WLDS;
    char* myrow = wbase + lane * ROWB;
    const int jn = lane & 15;
    const int g  = lane >> 4;
    const int xb = (lane & 7) << 4;   // own-row swizzle
    const int xr = (jn & 7) << 4;     // A-row swizzle for fragment reads

    // ---- load obs row (12x float4, coalesced); cvt to packed bf16 + agent idx ----
    unsigned op[24];
    float sidx = 0.0f;
    {
        const float4* g4 = reinterpret_cast<const float4*>(obs + (size_t)b * 48);
        #pragma unroll
        for (int q = 0; q < 12; ++q) {
            float4 t = g4[q];
            float va[4] = {t.x, t.y, t.z, t.w};
            #pragma unroll
            for (int e = 0; e < 4; ++e) {
                int E = 4*q + e;
                if ((E % 3) == 1 && (E / 3) > 0)   // channel-1 one-hot, value 1.0
                    sidx = fmaf(va[e], (float)(E / 3), sidx);
            }
            op[2*q]   = cvtpkbf(va[0], va[1]);
            op[2*q+1] = cvtpkbf(va[2], va[3]);
        }
    }
    const int idx = (int)(sidx + 0.5f);
    const int ai = idx >> 2;
    const int aj = idx & 3;
    const bool rok0 = (ai >= 1), rok2 = (ai <= 2);
    const bool cok0 = (aj >= 1), cok2 = (aj <= 2);

    // ---- write own obs row to A-area (swizzled; 6 data + 2 zero slots) ----
    {
        #pragma unroll
        for (int q = 0; q < 6; ++q) {
            u32x4 v = { op[4*q], op[4*q+1], op[4*q+2], op[4*q+3] };
            *reinterpret_cast<u32x4*>(myrow + ((q * 16) ^ xb)) = v;
        }
        u32x4 z = {0u, 0u, 0u, 0u};
        *reinterpret_cast<u32x4*>(myrow + ((6 * 16) ^ xb)) = z;   // shorts 48..55
        *reinterpret_cast<u32x4*>(myrow + ((7 * 16) ^ xb)) = z;   // shorts 56..63
    }
    MEMFENCE;   // A-writes before gather reads (compiler order; HW in-order)

    // ---- sub_state gather (features 0..26); OOB -> zero sentinel at short 48 ----
    float lg0 = Lb[0], lg1 = Lb[1], lg2 = Lb[2], lg3 = Lb[3];
    {
        const int base3 = 3*idx - 15;
        #pragma unroll
        for (int dh = 0; dh < 3; ++dh)
            #pragma unroll
            for (int dw = 0; dw < 3; ++dw) {
                bool ok = (dh == 0 ? rok0 : dh == 2 ? rok2 : true) &&
                          (dw == 0 ? cok0 : dw == 2 ? cok2 : true);
                int ba = ok ? (base3 + 3*(4*dh + dw)) : 48;
                float s0 = b2f(*reinterpret_cast<const short*>(myrow + (((ba+0)*2) ^ xb)));
                float s1 = b2f(*reinterpret_cast<const short*>(myrow + (((ba+1)*2) ^ xb)));
                float s2 = b2f(*reinterpret_cast<const short*>(myrow + (((ba+2)*2) ^ xb)));
                int f = (dh*3 + dw) * 3;
                lg0 = fmaf(s0, LW[0*36+f], fmaf(s1, LW[0*36+f+1], fmaf(s2, LW[0*36+f+2], lg0)));
                lg1 = fmaf(s0, LW[1*36+f], fmaf(s1, LW[1*36+f+1], fmaf(s2, LW[1*36+f+2], lg1)));
                lg2 = fmaf(s0, LW[2*36+f], fmaf(s1, LW[2*36+f+1], fmaf(s2, LW[2*36+f+2], lg2)));
                lg3 = fmaf(s0, LW[3*36+f], fmaf(s1, LW[3*36+f+1], fmaf(s2, LW[3*36+f+2], lg3)));
            }
    }

    // ---- A-fragments frag0 only (k=0..31): row m*16+jn, slot g, swizzled ----
    short8 afrag0[4];
    #pragma unroll
    for (int m = 0; m < 4; ++m) {
        const char* rp = wbase + (m*16 + jn) * ROWB;
        afrag0[m] = *reinterpret_cast<const short8*>(rp + ((16*g) ^ xr));
    }
    MEMFENCE;   // frag0 reads before strip scatter overwrites k=0..31 (WAR; in-order DS)

    // ---- 3 column-tiles with incremental f16 packing of rin/rout/p ----
    unsigned rinp[4][2], routp[4][2], pp[4][2];
    float rv[16];
    const float b0 = Phib[jn], b1 = Phib[16 + jn], b2 = Phib[32 + jn];

    tile_pass(0, wbase, jn, g, xb, xr, afrag0, PhiW, b0, rv);   // cols 0..15
    rinp[0][0] = pkrtz(rv[0], rv[6]);  routp[0][0] = pkrtz(rv[1], rv[7]);  pp[0][0] = pkrtz(rv[2], rv[8]);
    rinp[0][1] = pkrtz(rv[3], rv[9]);  routp[0][1] = pkrtz(rv[4], rv[10]); pp[0][1] = pkrtz(rv[5], rv[11]);
    float c4r = rv[12], c4o = rv[13], c4p = rv[14], c5r = rv[15];

    tile_pass(1, wbase, jn, g, xb, xr, afrag0, PhiW, b1, rv);   // cols 16..31
    {
        float c5o = rv[0], c5p = rv[1];
        rinp[1][0] = pkrtz(c4r, rv[2]); routp[1][0] = pkrtz(c4o, rv[3]); pp[1][0] = pkrtz(c4p, rv[4]);
        rinp[1][1] = pkrtz(c5r, rv[5]); routp[1][1] = pkrtz(c5o, rv[6]); pp[1][1] = pkrtz(c5p, rv[7]);
    }
    float c8r = rv[8],  c8o = rv[9],  c8p = rv[10];
    float c9r = rv[11], c9o = rv[12], c9p = rv[13];
    float c10r = rv[14], c10o = rv[15];

    tile_pass(2, wbase, jn, g, xb, xr, afrag0, PhiW, b2, rv);   // cols 32..47
    rinp[2][0] = pkrtz(c8r, c10r);     routp[2][0] = pkrtz(c8o, c10o);    pp[2][0] = pkrtz(c8p, rv[0]);
    rinp[2][1] = pkrtz(c9r, rv[1]);    routp[2][1] = pkrtz(c9o, rv[2]);   pp[2][1] = pkrtz(c9p, rv[3]);
    rinp[3][0] = pkrtz(rv[4], rv[10]); routp[3][0] = pkrtz(rv[5], rv[11]); pp[3][0] = pkrtz(rv[6], rv[12]);
    rinp[3][1] = pkrtz(rv[7], rv[13]); routp[3][1] = pkrtz(rv[8], rv[14]); pp[3][1] = pkrtz(rv[9], rv[15]);

    // ---- build per-direction a* = rin_neighbor - rout in packed f16 ----
    unsigned aL2[4][2], aR2[4][2], aU2[4][2], aD2[4][2];
    #pragma unroll
    for (int h = 0; h < 4; ++h) {
        aL2[h][0] = pksub(rinp[h][1] << 16, routp[h][0]);
        aL2[h][1] = pksub(rinp[h][0], routp[h][1]);
        aR2[h][0] = pksub(rinp[h][1], routp[h][0]);
        aR2[h][1] = pksub(rinp[h][0] >> 16, routp[h][1]);
        #pragma unroll
        for (int j = 0; j < 2; ++j) {
            aU2[h][j] = (h > 0) ? pksub(rinp[h-1][j], routp[h][j]) : pkneg(routp[0][j]);
            aD2[h][j] = (h < 3) ? pksub(rinp[h+1][j], routp[h][j]) : pkneg(routp[3][j]);
        }
    }
    // half-masked p for boundary-exact op_sel fmas
    unsigned pLm[4], pRm[4];
    #pragma unroll
    for (int h = 0; h < 4; ++h) {
        pLm[h] = pp[h][0] & 0xFFFF0000u;
        pRm[h] = pp[h][1] & 0x0000FFFFu;
    }

    // ---- K=20 VI steps, packed f16, unrolled x2 (ping-pong) ----
    unsigned Vp[4][2], Vn[4][2];
    #pragma unroll
    for (int h = 0; h < 4; ++h) { Vp[h][0] = 0u; Vp[h][1] = 0u; }
    #pragma unroll 1
    for (int s = 0; s < 10; ++s) {
        vistep(Vp, Vn, pp, pLm, pRm, aL2, aR2, aU2, aD2);
        vistep(Vn, Vp, pp, pLm, pRm, aL2, aR2, aU2, aD2);
    }

    // ---- V to own row words 0..15 (+zero sentinel word 16), swizzled ----
    {
        #pragma unroll
        for (int h = 0; h < 4; ++h) {
            h2 a = __builtin_bit_cast(h2, Vp[h][0]);
            h2 c = __builtin_bit_cast(h2, Vp[h][1]);
            *reinterpret_cast<f32x4*>(myrow + ((h * 16) ^ xb)) =
                (f32x4){(float)a[0], (float)c[0], (float)a[1], (float)c[1]};
        }
        *reinterpret_cast<float*>(myrow + (64 ^ xb)) = 0.0f;   // word 16 sentinel
    }
    MEMFENCE;   // V writes before V gather reads (RAW; in-order DS)
    {
        const int base1 = idx - 5;
        #pragma unroll
        for (int dh = 0; dh < 3; ++dh)
            #pragma unroll
            for (int dw = 0; dw < 3; ++dw) {
                bool ok = (dh == 0 ? rok0 : dh == 2 ? rok2 : true) &&
                          (dw == 0 ? cok0 : dw == 2 ? cok2 : true);
                int ba = ok ? (base1 + 4*dh + dw) : 16;   // 16 -> zero sentinel
                float v = *reinterpret_cast<const float*>(myrow + ((ba * 4) ^ xb));
                int f = 27 + dh*3 + dw;
                lg0 = fmaf(v, LW[0*36+f], lg0);
                lg1 = fmaf(v, LW[1*36+f], lg1);
                lg2 = fmaf(v, LW[2*36+f], lg2);
                lg3 = fmaf(v, LW[3*36+f], lg3);
            }
    }

    reinterpret_cast<float4*>(out)[b] = make_float4(lg0, lg1, lg2, lg3);
}

extern "C" void kernel_launch(void* const* d_in, const int* in_sizes, int n_in,
                              void* d_out, int out_size, void* d_ws, size_t ws_size,
                              hipStream_t stream) {
    const float* obs  = (const float*)d_in[0];
    const float* PhiW = (const float*)d_in[1];
    const float* Phib = (const float*)d_in[2];
    const float* LW   = (const float*)d_in[3];
    const float* Lb   = (const float*)d_in[4];
    float* out = (float*)d_out;

    const int Btot = in_sizes[0] / 48;   // 1,000,000
    const int grid = (Btot + BT - 1) / BT;
    hipLaunchKernelGGL(vin_kernel, dim3(grid), dim3(BT), 0, stream,
                       obs, PhiW, Phib, LW, Lb, out, Btot);
}

// Round 16
// 64.339 us; speedup vs baseline: 1.1702x; 1.1702x over previous
//
#include <hip/hip_runtime.h>

#define BT 256           // 4 waves per block
#define ROWB 128         // LDS row stride: 32 words = 8 x 16B slots
#define WLDS (64 * ROWB) // 8192 B per wave -> 32768 B per block
// A-row (logical): 64 shorts = 48 bf16 obs + 16 zeros (K-pad + gather sentinel)
// strip (per column-tile): logical words 0..15, reused 3x (overlays A)
// V-area (post-VI): logical words 0..15 + zero sentinel word 16
// All LDS accesses XOR-swizzled per row: phys_byte = logical_byte ^ ((row&7)<<4)

// Compiler-only fence: orders LDS ops across overlay phases (HW DS is in-order per wave).
#define MEMFENCE asm volatile("" ::: "memory")

typedef __attribute__((ext_vector_type(8))) short short8;
typedef __attribute__((ext_vector_type(4))) float f32x4;
typedef __attribute__((ext_vector_type(4))) unsigned int u32x4;
typedef _Float16 h2 __attribute__((ext_vector_type(2)));

__device__ inline unsigned cvtpkbf(float a, float b) {   // 2xf32 -> 2xbf16 (RNE)
    unsigned d;
    asm("v_cvt_pk_bf16_f32 %0, %1, %2" : "=v"(d) : "v"(a), "v"(b));
    return d;
}
__device__ inline float b2f(short s) {
    unsigned u = ((unsigned)(unsigned short)s) << 16;
    return __builtin_bit_cast(float, u);
}
__device__ inline unsigned pkrtz(float a, float b) {     // 2xf32 -> 2xf16 (RTZ)
    unsigned d;
    asm("v_cvt_pkrtz_f16_f32 %0, %1, %2" : "=v"(d) : "v"(a), "v"(b));
    return d;
}
__device__ inline unsigned pkfma(unsigned a, unsigned b, unsigned c) {
    unsigned d;
    asm("v_pk_fma_f16 %0, %1, %2, %3" : "=v"(d) : "v"(a), "v"(b), "v"(c));
    return d;
}
// fma with src1 halves SWAPPED: res.lo = a.lo*b.hi + c.lo ; res.hi = a.hi*b.lo + c.hi
__device__ inline unsigned pkfma_swap1(unsigned a, unsigned b, unsigned c) {
    unsigned d;
    asm("v_pk_fma_f16 %0, %1, %2, %3 op_sel:[0,1,0] op_sel_hi:[1,0,1]"
        : "=v"(d) : "v"(a), "v"(b), "v"(c));
    return d;
}
__device__ inline unsigned pkmax(unsigned a, unsigned b) {
    unsigned d;
    asm("v_pk_max_f16 %0, %1, %2" : "=v"(d) : "v"(a), "v"(b));
    return d;
}
__device__ inline unsigned pksub(unsigned a, unsigned b) {   // a - b
    unsigned d;
    asm("v_pk_add_f16 %0, %1, %2 neg_lo:[0,1] neg_hi:[0,1]" : "=v"(d) : "v"(a), "v"(b));
    return d;
}
__device__ inline unsigned pkneg(unsigned b) {               // -b
    unsigned d;
    asm("v_pk_add_f16 %0, 0, %1 neg_lo:[0,1] neg_hi:[0,1]" : "=v"(d) : "v"(b));
    return d;
}

// one VI step; pack (h,j): lo=V[h][j], hi=V[h][j+2]
// Boundary halves via half-masked p (pLm.lo=0, pRm.hi=0) + op_sel swap (exact).
__device__ inline void vistep(const unsigned (&S)[4][2], unsigned (&D)[4][2],
                              const unsigned (&pp)[4][2],
                              const unsigned (&pLm)[4], const unsigned (&pRm)[4],
                              const unsigned (&aL)[4][2], const unsigned (&aR)[4][2],
                              const unsigned (&aU)[4][2], const unsigned (&aD)[4][2])
{
    #pragma unroll
    for (int h = 0; h < 4; ++h) {
        {
            unsigned cL = pkfma_swap1(pLm[h], S[h][1], aL[h][0]);
            unsigned cR = pkfma(pp[h][0], S[h][1], aR[h][0]);
            unsigned tU = (h > 0) ? pkfma(pp[h][0], S[h-1][0], aU[h][0]) : aU[h][0];
            unsigned tD = (h < 3) ? pkfma(pp[h][0], S[h+1][0], aD[h][0]) : aD[h][0];
            unsigned m1 = pkmax(S[h][0], cL);
            unsigned m2 = pkmax(cR, tU);
            D[h][0] = pkmax(pkmax(m1, m2), tD);
        }
        {
            unsigned cL = pkfma(pp[h][1], S[h][0], aL[h][1]);
            unsigned cR = pkfma_swap1(pRm[h], S[h][0], aR[h][1]);
            unsigned tU = (h > 0) ? pkfma(pp[h][1], S[h-1][1], aU[h][1]) : aU[h][1];
            unsigned tD = (h < 3) ? pkfma(pp[h][1], S[h+1][1], aD[h][1]) : aD[h][1];
            unsigned m1 = pkmax(S[h][1], cL);
            unsigned m2 = pkmax(cR, tU);
            D[h][1] = pkmax(pkmax(m1, m2), tD);
        }
    }
}

// MFMA for one column-tile (no LDS traffic: bfrag from global, afrag in regs)
__device__ inline void tile_mfma(int n, int jn, int g,
                                 const short8 (&afrag)[4][2],
                                 const float* __restrict__ PhiW, float bn,
                                 f32x4 (&acc)[4])
{
    const float* wrow = PhiW + (16*n + jn) * 48;
    short8 bf0, bf1;
    {
        float4 q0 = *reinterpret_cast<const float4*>(wrow + 8*g);
        float4 q1 = *reinterpret_cast<const float4*>(wrow + 8*g + 4);
        u32x4 t0;
        t0[0] = cvtpkbf(q0.x, q0.y); t0[1] = cvtpkbf(q0.z, q0.w);
        t0[2] = cvtpkbf(q1.x, q1.y); t0[3] = cvtpkbf(q1.z, q1.w);
        bf0 = __builtin_bit_cast(short8, t0);
        u32x4 tz = {0u, 0u, 0u, 0u};
        if (g < 2) {   // k = 32+8g..+7 valid only for g<2; k>=48 zero pad
            float4 q2 = *reinterpret_cast<const float4*>(wrow + 32 + 8*g);
            float4 q3 = *reinterpret_cast<const float4*>(wrow + 36 + 8*g);
            tz[0] = cvtpkbf(q2.x, q2.y); tz[1] = cvtpkbf(q2.z, q2.w);
            tz[2] = cvtpkbf(q3.x, q3.y); tz[3] = cvtpkbf(q3.z, q3.w);
        }
        bf1 = __builtin_bit_cast(short8, tz);
    }
    #pragma unroll
    for (int m = 0; m < 4; ++m) {
        acc[m] = (f32x4){bn, bn, bn, bn};
        acc[m] = __builtin_amdgcn_mfma_f32_16x16x32_bf16(afrag[m][0], bf0, acc[m], 0, 0, 0);
        acc[m] = __builtin_amdgcn_mfma_f32_16x16x32_bf16(afrag[m][1], bf1, acc[m], 0, 0, 0);
    }
}

// scatter D to strip: lane holds col 16n+jn of rows R=m*16+4g+r; word jn, swizzled
__device__ inline void tile_scatter(char* wbase, int jn, int g, const f32x4 (&acc)[4])
{
    #pragma unroll
    for (int m = 0; m < 4; ++m)
        #pragma unroll
        for (int r = 0; r < 4; ++r) {
            int R = m*16 + 4*g + r;
            int byte = R * ROWB + ((jn * 4) ^ (((4*g + r) & 7) << 4));
            *reinterpret_cast<float*>(wbase + byte) = acc[m][r];
        }
}

// readback own row's 16 cols of current tile (4 x b128, slot-contiguous)
__device__ inline void tile_readback(char* myrow, int xb, float (&rv)[16])
{
    #pragma unroll
    for (int s = 0; s < 4; ++s) {
        f32x4 t = *reinterpret_cast<const f32x4*>(myrow + ((s * 16) ^ xb));
        rv[4*s+0] = t[0]; rv[4*s+1] = t[1]; rv[4*s+2] = t[2]; rv[4*s+3] = t[3];
    }
}

__global__ __launch_bounds__(BT, 4) void vin_kernel(
    const float* __restrict__ obs,
    const float* __restrict__ PhiW,
    const float* __restrict__ Phib,
    const float* __restrict__ LW,
    const float* __restrict__ Lb,
    float* __restrict__ out, int Btot)
{
    __shared__ __align__(16) char smem[4 * WLDS];   // 32768 B
    const int tid  = threadIdx.x;
    const int lane = tid & 63;
    const int wid  = tid >> 6;
    const int b    = blockIdx.x * BT + tid;
    // Btot % 64 == 0, waves entirely in or out; no barriers -> early return safe
    if (b >= Btot) return;

    char* wbase = smem + wid * WLDS;
    char* myrow = wbase + lane * ROWB;
    const int jn = lane & 15;
    const int g  = lane >> 4;
    const int xb = (lane & 7) << 4;   // own-row swizzle
    const int xr = (jn & 7) << 4;     // A-row swizzle for fragment reads

    // ---- load obs row (12x float4, coalesced); cvt to packed bf16 + agent idx ----
    unsigned op[24];
    float sidx = 0.0f;
    {
        const float4* g4 = reinterpret_cast<const float4*>(obs + (size_t)b * 48);
        #pragma unroll
        for (int q = 0; q < 12; ++q) {
            float4 t = g4[q];
            float va[4] = {t.x, t.y, t.z, t.w};
            #pragma unroll
            for (int e = 0; e < 4; ++e) {
                int E = 4*q + e;
                if ((E % 3) == 1 && (E / 3) > 0)   // channel-1 one-hot, value 1.0
                    sidx = fmaf(va[e], (float)(E / 3), sidx);
            }
            op[2*q]   = cvtpkbf(va[0], va[1]);
            op[2*q+1] = cvtpkbf(va[2], va[3]);
        }
    }
    const int idx = (int)(sidx + 0.5f);
    const int ai = idx >> 2;
    const int aj = idx & 3;
    const bool rok0 = (ai >= 1), rok2 = (ai <= 2);
    const bool cok0 = (aj >= 1), cok2 = (aj <= 2);

    // ---- write own obs row to A-area (swizzled; 6 data + 2 zero slots) ----
    {
        #pragma unroll
        for (int q = 0; q < 6; ++q) {
            u32x4 v = { op[4*q], op[4*q+1], op[4*q+2], op[4*q+3] };
            *reinterpret_cast<u32x4*>(myrow + ((q * 16) ^ xb)) = v;
        }
        u32x4 z = {0u, 0u, 0u, 0u};
        *reinterpret_cast<u32x4*>(myrow + ((6 * 16) ^ xb)) = z;   // shorts 48..55
        *reinterpret_cast<u32x4*>(myrow + ((7 * 16) ^ xb)) = z;   // shorts 56..63
    }
    MEMFENCE;   // A-writes before gather reads (compiler order; HW in-order)

    // ---- sub_state gather (features 0..26); OOB -> zero sentinel at short 48 ----
    float lg0 = Lb[0], lg1 = Lb[1], lg2 = Lb[2], lg3 = Lb[3];
    {
        const int base3 = 3*idx - 15;
        #pragma unroll
        for (int dh = 0; dh < 3; ++dh)
            #pragma unroll
            for (int dw = 0; dw < 3; ++dw) {
                bool ok = (dh == 0 ? rok0 : dh == 2 ? rok2 : true) &&
                          (dw == 0 ? cok0 : dw == 2 ? cok2 : true);
                int ba = ok ? (base3 + 3*(4*dh + dw)) : 48;
                float s0 = b2f(*reinterpret_cast<const short*>(myrow + (((ba+0)*2) ^ xb)));
                float s1 = b2f(*reinterpret_cast<const short*>(myrow + (((ba+1)*2) ^ xb)));
                float s2 = b2f(*reinterpret_cast<const short*>(myrow + (((ba+2)*2) ^ xb)));
                int f = (dh*3 + dw) * 3;
                lg0 = fmaf(s0, LW[0*36+f], fmaf(s1, LW[0*36+f+1], fmaf(s2, LW[0*36+f+2], lg0)));
                lg1 = fmaf(s0, LW[1*36+f], fmaf(s1, LW[1*36+f+1], fmaf(s2, LW[1*36+f+2], lg1)));
                lg2 = fmaf(s0, LW[2*36+f], fmaf(s1, LW[2*36+f+1], fmaf(s2, LW[2*36+f+2], lg2)));
                lg3 = fmaf(s0, LW[3*36+f], fmaf(s1, LW[3*36+f+1], fmaf(s2, LW[3*36+f+2], lg3)));
            }
    }

    // ---- A-fragments: lane reads row m*16+jn, slots g and 4+g (swizzled) ----
    short8 afrag[4][2];
    #pragma unroll
    for (int m = 0; m < 4; ++m) {
        const char* rp = wbase + (m*16 + jn) * ROWB;
        afrag[m][0] = *reinterpret_cast<const short8*>(rp + ((16*g) ^ xr));
        afrag[m][1] = *reinterpret_cast<const short8*>(rp + ((64 + 16*g) ^ xr));
    }
    MEMFENCE;   // afrag reads before strip scatter overwrites A (WAR; in-order DS)

    // ---- 3 column-tiles, software-pipelined: MFMA(t+1) hides readback(t) wait ----
    unsigned rinp[4][2], routp[4][2], pp[4][2];
    float rv[16];
    const float b0 = Phib[jn], b1 = Phib[16 + jn], b2 = Phib[32 + jn];
    f32x4 accA[4], accB[4];

    tile_mfma(0, jn, g, afrag, PhiW, b0, accA);
    tile_scatter(wbase, jn, g, accA);        // t0 -> strip
    tile_mfma(1, jn, g, afrag, PhiW, b1, accB);   // overlaps t0 scatter/readback
    MEMFENCE;
    tile_readback(myrow, xb, rv);            // t0 results (issue; data later)
    MEMFENCE;
    tile_scatter(wbase, jn, g, accB);        // t1 -> strip (in-order DS: WAR safe)
    tile_mfma(2, jn, g, afrag, PhiW, b2, accA);   // overlaps t1 scatter + t0 data
    // pack t0 (cols 0..15) -- rv data long since arrived
    rinp[0][0] = pkrtz(rv[0], rv[6]);  routp[0][0] = pkrtz(rv[1], rv[7]);  pp[0][0] = pkrtz(rv[2], rv[8]);
    rinp[0][1] = pkrtz(rv[3], rv[9]);  routp[0][1] = pkrtz(rv[4], rv[10]); pp[0][1] = pkrtz(rv[5], rv[11]);
    float c4r = rv[12], c4o = rv[13], c4p = rv[14], c5r = rv[15];
    MEMFENCE;
    tile_readback(myrow, xb, rv);            // t1 results
    MEMFENCE;
    tile_scatter(wbase, jn, g, accA);        // t2 -> strip
    // pack t1 (cols 16..31)
    {
        float c5o = rv[0], c5p = rv[1];
        rinp[1][0] = pkrtz(c4r, rv[2]); routp[1][0] = pkrtz(c4o, rv[3]); pp[1][0] = pkrtz(c4p, rv[4]);
        rinp[1][1] = pkrtz(c5r, rv[5]); routp[1][1] = pkrtz(c5o, rv[6]); pp[1][1] = pkrtz(c5p, rv[7]);
    }
    float c8r = rv[8],  c8o = rv[9],  c8p = rv[10];
    float c9r = rv[11], c9o = rv[12], c9p = rv[13];
    float c10r = rv[14], c10o = rv[15];
    MEMFENCE;
    tile_readback(myrow, xb, rv);            // t2 results
    MEMFENCE;
    // pack t2 (cols 32..47)
    rinp[2][0] = pkrtz(c8r, c10r);     routp[2][0] = pkrtz(c8o, c10o);    pp[2][0] = pkrtz(c8p, rv[0]);
    rinp[2][1] = pkrtz(c9r, rv[1]);    routp[2][1] = pkrtz(c9o, rv[2]);   pp[2][1] = pkrtz(c9p, rv[3]);
    rinp[3][0] = pkrtz(rv[4], rv[10]); routp[3][0] = pkrtz(rv[5], rv[11]); pp[3][0] = pkrtz(rv[6], rv[12]);
    rinp[3][1] = pkrtz(rv[7], rv[13]); routp[3][1] = pkrtz(rv[8], rv[14]); pp[3][1] = pkrtz(rv[9], rv[15]);

    // ---- build per-direction a* = rin_neighbor - rout in packed f16 ----
    unsigned aL2[4][2], aR2[4][2], aU2[4][2], aD2[4][2];
    #pragma unroll
    for (int h = 0; h < 4; ++h) {
        aL2[h][0] = pksub(rinp[h][1] << 16, routp[h][0]);
        aL2[h][1] = pksub(rinp[h][0], routp[h][1]);
        aR2[h][0] = pksub(rinp[h][1], routp[h][0]);
        aR2[h][1] = pksub(rinp[h][0] >> 16, routp[h][1]);
        #pragma unroll
        for (int j = 0; j < 2; ++j) {
            aU2[h][j] = (h > 0) ? pksub(rinp[h-1][j], routp[h][j]) : pkneg(routp[0][j]);
            aD2[h][j] = (h < 3) ? pksub(rinp[h+1][j], routp[h][j]) : pkneg(routp[3][j]);
        }
    }
    // half-masked p for boundary-exact op_sel fmas
    unsigned pLm[4], pRm[4];
    #pragma unroll
    for (int h = 0; h < 4; ++h) {
        pLm[h] = pp[h][0] & 0xFFFF0000u;
        pRm[h] = pp[h][1] & 0x0000FFFFu;
    }

    // ---- K=20 VI steps, packed f16, unrolled x2 (ping-pong) ----
    unsigned Vp[4][2], Vn[4][2];
    #pragma unroll
    for (int h = 0; h < 4; ++h) { Vp[h][0] = 0u; Vp[h][1] = 0u; }
    #pragma unroll 1
    for (int s = 0; s < 10; ++s) {
        vistep(Vp, Vn, pp, pLm, pRm, aL2, aR2, aU2, aD2);
        vistep(Vn, Vp, pp, pLm, pRm, aL2, aR2, aU2, aD2);
    }

    // ---- V to own row words 0..15 (+zero sentinel word 16), swizzled ----
    {
        #pragma unroll
        for (int h = 0; h < 4; ++h) {
            h2 a = __builtin_bit_cast(h2, Vp[h][0]);
            h2 c = __builtin_bit_cast(h2, Vp[h][1]);
            *reinterpret_cast<f32x4*>(myrow + ((h * 16) ^ xb)) =
                (f32x4){(float)a[0], (float)c[0], (float)a[1], (float)c[1]};
        }
        *reinterpret_cast<float*>(myrow + (64 ^ xb)) = 0.0f;   // word 16 sentinel
    }
    MEMFENCE;   // V writes before V gather reads (RAW; in-order DS)
    {
        const int base1 = idx - 5;
        #pragma unroll
        for (int dh = 0; dh < 3; ++dh)
            #pragma unroll
            for (int dw = 0; dw < 3; ++dw) {
                bool ok = (dh == 0 ? rok0 : dh == 2 ? rok2 : true) &&
                          (dw == 0 ? cok0 : dw == 2 ? cok2 : true);
                int ba = ok ? (base1 + 4*dh + dw) : 16;   // 16 -> zero sentinel
                float v = *reinterpret_cast<const float*>(myrow + ((ba * 4) ^ xb));
                int f = 27 + dh*3 + dw;
                lg0 = fmaf(v, LW[0*36+f], lg0);
                lg1 = fmaf(v, LW[1*36+f], lg1);
                lg2 = fmaf(v, LW[2*36+f], lg2);
                lg3 = fmaf(v, LW[3*36+f], lg3);
            }
    }

    reinterpret_cast<float4*>(out)[b] = make_float4(lg0, lg1, lg2, lg3);
}

extern "C" void kernel_launch(void* const* d_in, const int* in_sizes, int n_in,
                              void* d_out, int out_size, void* d_ws, size_t ws_size,
                              hipStream_t stream) {
    const float* obs  = (const float*)d_in[0];
    const float* PhiW = (const float*)d_in[1];
    const float* Phib = (const float*)d_in[2];
    const float* LW   = (const float*)d_in[3];
    const float* Lb   = (const float*)d_in[4];
    float* out = (float*)d_out;

    const int Btot = in_sizes[0] / 48;   // 1,000,000
    const int grid = (Btot + BT - 1) / BT;
    hipLaunchKernelGGL(vin_kernel, dim3(grid), dim3(BT), 0, stream,
                       obs, PhiW, Phib, LW, Lb, out, Btot);
}